// Round 1
// baseline (1034.233 us; speedup 1.0000x reference)
//
#include <hip/hip_runtime.h>
#include <hip/hip_bf16.h>

// ---------------------------------------------------------------------------
// PlanStructuredNetwork: tree of MLPs.
//   leaf:  x(B,1024,32) -> unit(sW*)  -> cur(B,1024,32)
//   join levels n=512..1: x = [feats(32) | curL(32) | curR(32)] -> unit(jW*)
// Strategy (round 1):
//   * fp16 MFMA (v_mfma_f32_16x16x32_f16), fp32 accumulation.
//   * transposed chain: D^T = W^T x^T, so node index is always the N dim
//     (lane&15) for A/B/C — layer handoff = pack + wide LDS round trip.
//   * bias via augmented K-step (ones column in x, bias row in W^T).
//   * weights pre-transposed+augmented to fp16 in d_ws (prep kernel) and
//     held RESIDENT in VGPRs; block = 2 waves, wave w owns output rows
//     [64w,64w+64) of layers 1/2 and [16w,16w+16) of layer 3.
//   * flat row index g = b*n + i  =>  children are rows 2g, 2g+1 at every
//     level; feats row = b*1023 + off + i.
//   * intermediates (fp16 [row][32]) ping-pong in d_ws.
// ws usage: 151552 B weights + 128 MB curA + 64 MB curB  (~192.2 MB).
// ---------------------------------------------------------------------------

typedef _Float16 f16;
typedef _Float16 f16x8 __attribute__((ext_vector_type(8)));
typedef _Float16 f16x4 __attribute__((ext_vector_type(4)));
typedef float    f32x4 __attribute__((ext_vector_type(4)));

#define MFMA16(a, b, c) __builtin_amdgcn_mfma_f32_16x16x32_f16((a), (b), (c), 0, 0, 0)

// ws element offsets (f16) of the augmented-transposed weights
#define OFF_S1 0       // [128][64]   leaf L1 (K=32 +bias +pad)
#define OFF_S2 8192    // [128][160]  L2 (K=128 +bias +pad)
#define OFF_S3 28672   // [32][160]   L3
#define OFF_J1 33792   // [128][128]  join L1 (K=96 +bias +pad)
#define OFF_J2 50176   // [128][160]
#define OFF_J3 70656   // [32][160]
#define W_TOTAL 75776
#define CURA_BYTE_OFF 151552            // = W_TOTAL*2, 256B aligned

__global__ void prep_weights(const float* __restrict__ sW1, const float* __restrict__ sb1,
                             const float* __restrict__ sW2, const float* __restrict__ sb2,
                             const float* __restrict__ sW3, const float* __restrict__ sb3,
                             const float* __restrict__ jW1, const float* __restrict__ jb1,
                             const float* __restrict__ jW2, const float* __restrict__ jb2,
                             const float* __restrict__ jW3, const float* __restrict__ jb3,
                             f16* __restrict__ wbuf)
{
    int idx = blockIdx.x * 256 + threadIdx.x;
    if (idx >= W_TOTAL) return;
    const float *W, *bias;
    int off, M, Kaug, Kr;
    if (idx < OFF_S2)      { off = OFF_S1; M = 128; Kaug = 64;  Kr = 32;  W = sW1; bias = sb1; }
    else if (idx < OFF_S3) { off = OFF_S2; M = 128; Kaug = 160; Kr = 128; W = sW2; bias = sb2; }
    else if (idx < OFF_J1) { off = OFF_S3; M = 32;  Kaug = 160; Kr = 128; W = sW3; bias = sb3; }
    else if (idx < OFF_J2) { off = OFF_J1; M = 128; Kaug = 128; Kr = 96;  W = jW1; bias = jb1; }
    else if (idx < OFF_J3) { off = OFF_J2; M = 128; Kaug = 160; Kr = 128; W = jW2; bias = jb2; }
    else                   { off = OFF_J3; M = 32;  Kaug = 160; Kr = 128; W = jW3; bias = jb3; }
    int r = idx - off;
    int m = r / Kaug;
    int k = r - m * Kaug;
    float v = (k < Kr) ? W[(size_t)k * M + m] : ((k == Kr) ? bias[m] : 0.0f);
    wbuf[idx] = (f16)v;
}

// One fused 3-layer MLP level. Each block: 128 threads = 2 waves, 16 rows/group.
template <bool LEAF>
__global__ __launch_bounds__(128, 2)
void mlp_level(const float* __restrict__ feats,     // leaf_feats or internal_feats
               const f16*   __restrict__ cur_in,    // prev level [row][32] f16 (join only)
               f16*         __restrict__ cur_out,   // this level [row][32] f16
               float*       __restrict__ out_final, // d_out (last level)
               const f16*   __restrict__ W1t,
               const f16*   __restrict__ W2t,
               const f16*   __restrict__ W3t,
               int rows, int log2n, int foff, int is_last)
{
    constexpr int K1    = LEAF ? 64 : 128;   // augmented K of layer 1
    constexpr int NK1   = LEAF ? 2 : 4;      // K-steps of layer 1
    constexpr int PITCH = 168;               // f16 per LDS row = 336 B (16B-mult, padded)

    __shared__ __align__(16) f16 h1[16 * PITCH];
    __shared__ __align__(16) f16 h2[16 * PITCH];

    const int tid  = threadIdx.x;
    const int wave = tid >> 6;
    const int lane = tid & 63;
    const int n    = lane & 15;   // node-local (N dim) / weight row-local (A's m)
    const int q    = lane >> 4;   // quad

    // init augmented activation columns once: col 128 = 1.0, cols 129..159 = 0
    for (int t = tid; t < 1024; t += 128) {
        int buf = t >> 9, rr = (t >> 5) & 15, cc = t & 31;
        f16 v = (cc == 0) ? (f16)1.0f : (f16)0.0f;
        (buf ? h2 : h1)[rr * PITCH + 128 + cc] = v;
    }

    // resident weights: A[m][k], m = 16*mt + n (wave owns 64-row half), k = 32*ks + 8*q + j
    f16x8 A1[4][NK1], A2[4][5], A3[5];
#pragma unroll
    for (int mt = 0; mt < 4; ++mt)
#pragma unroll
        for (int ks = 0; ks < NK1; ++ks)
            A1[mt][ks] = *(const f16x8*)(W1t + (size_t)(64 * wave + 16 * mt + n) * K1 + 32 * ks + 8 * q);
#pragma unroll
    for (int mt = 0; mt < 4; ++mt)
#pragma unroll
        for (int ks = 0; ks < 5; ++ks)
            A2[mt][ks] = *(const f16x8*)(W2t + (size_t)(64 * wave + 16 * mt + n) * 160 + 32 * ks + 8 * q);
#pragma unroll
    for (int ks = 0; ks < 5; ++ks)
        A3[ks] = *(const f16x8*)(W3t + (size_t)(16 * wave + n) * 160 + 32 * ks + 8 * q);

    // augmented B fragment: ones row at k = K_real (first element of quad 0)
    f16x8 Baug;
#pragma unroll
    for (int j = 0; j < 8; ++j) Baug[j] = (f16)0.0f;
    if (q == 0) Baug[0] = (f16)1.0f;

    const f32x4 z = {0.0f, 0.0f, 0.0f, 0.0f};

    __syncthreads();

    for (int g0 = blockIdx.x * 16; g0 < rows; g0 += gridDim.x * 16) {
        const int g = g0 + n;   // this lane's node row (flat g = b*n_level + i)

        // ---------------- layer 1: B fragments (x^T) ----------------
        const float* frow;
        if constexpr (LEAF) {
            frow = feats + (size_t)g * 32;
        } else {
            const int b = g >> log2n;
            const int i = g & ((1 << log2n) - 1);
            frow = feats + ((size_t)b * 1023 + foff + i) * 32;
        }
        f32x4 fa = *(const f32x4*)(frow + 8 * q);
        f32x4 fb = *(const f32x4*)(frow + 8 * q + 4);
        f16x8 B1[NK1];
#pragma unroll
        for (int j = 0; j < 4; ++j) { B1[0][j] = (f16)fa[j]; B1[0][4 + j] = (f16)fb[j]; }
        if constexpr (!LEAF) {
            B1[1] = *(const f16x8*)(cur_in + (size_t)(2 * g) * 32 + 8 * q);       // curL
            B1[2] = *(const f16x8*)(cur_in + ((size_t)(2 * g) + 1) * 32 + 8 * q); // curR
        }
        B1[NK1 - 1] = Baug;

        f32x4 C1[4] = {z, z, z, z};
#pragma unroll
        for (int ks = 0; ks < NK1; ++ks)
#pragma unroll
            for (int mt = 0; mt < 4; ++mt)
                C1[mt] = MFMA16(A1[mt][ks], B1[ks], C1[mt]);

        // relu + pack -> h1[node][h], h = 64*wave + 16*mt + 4*q + reg  (b64 writes)
#pragma unroll
        for (int mt = 0; mt < 4; ++mt) {
            f16x4 pk;
            pk[0] = (f16)fmaxf(C1[mt][0], 0.0f);
            pk[1] = (f16)fmaxf(C1[mt][1], 0.0f);
            pk[2] = (f16)fmaxf(C1[mt][2], 0.0f);
            pk[3] = (f16)fmaxf(C1[mt][3], 0.0f);
            *(f16x4*)(h1 + n * PITCH + 64 * wave + 16 * mt + 4 * q) = pk;
        }
        __syncthreads();

        // ---------------- layer 2 ----------------
        f32x4 C2[4] = {z, z, z, z};
#pragma unroll
        for (int ks = 0; ks < 5; ++ks) {
            f16x8 Bf = *(const f16x8*)(h1 + n * PITCH + 32 * ks + 8 * q);
#pragma unroll
            for (int mt = 0; mt < 4; ++mt)
                C2[mt] = MFMA16(A2[mt][ks], Bf, C2[mt]);
        }
#pragma unroll
        for (int mt = 0; mt < 4; ++mt) {
            f16x4 pk;
            pk[0] = (f16)fmaxf(C2[mt][0], 0.0f);
            pk[1] = (f16)fmaxf(C2[mt][1], 0.0f);
            pk[2] = (f16)fmaxf(C2[mt][2], 0.0f);
            pk[3] = (f16)fmaxf(C2[mt][3], 0.0f);
            *(f16x4*)(h2 + n * PITCH + 64 * wave + 16 * mt + 4 * q) = pk;
        }
        __syncthreads();

        // ---------------- layer 3 (no relu) ----------------
        f32x4 C3 = z;
#pragma unroll
        for (int ks = 0; ks < 5; ++ks) {
            f16x8 Bf = *(const f16x8*)(h2 + n * PITCH + 32 * ks + 8 * q);
            C3 = MFMA16(A3[ks], Bf, C3);
        }

        if (is_last) {
            // out[b] = cur[:,0,0]: o=0 lives in wave 0, quad 0, reg 0
            if (wave == 0 && q == 0) out_final[g0 + n] = C3[0];
        } else {
            f16x4 pk;
            pk[0] = (f16)C3[0]; pk[1] = (f16)C3[1]; pk[2] = (f16)C3[2]; pk[3] = (f16)C3[3];
            *(f16x4*)(cur_out + (size_t)g * 32 + 16 * wave + 4 * q) = pk;
        }
        // no barrier needed here: next-iter h1/h2 writes are fenced by the
        // barriers above (all h1/h2 reads of this iter precede them per wave)
    }
}

extern "C" void kernel_launch(void* const* d_in, const int* in_sizes, int n_in,
                              void* d_out, int out_size, void* d_ws, size_t ws_size,
                              hipStream_t stream)
{
    const float* leaf_feats     = (const float*)d_in[0];
    const float* internal_feats = (const float*)d_in[1];
    const float* sW1 = (const float*)d_in[2];  const float* sb1 = (const float*)d_in[3];
    const float* sW2 = (const float*)d_in[4];  const float* sb2 = (const float*)d_in[5];
    const float* sW3 = (const float*)d_in[6];  const float* sb3 = (const float*)d_in[7];
    const float* jW1 = (const float*)d_in[8];  const float* jb1 = (const float*)d_in[9];
    const float* jW2 = (const float*)d_in[10]; const float* jb2 = (const float*)d_in[11];
    const float* jW3 = (const float*)d_in[12]; const float* jb3 = (const float*)d_in[13];

    f16* wbuf = (f16*)d_ws;
    f16* curA = (f16*)((char*)d_ws + CURA_BYTE_OFF);                  // 2048*1024*32 f16 = 128 MB
    f16* curB = (f16*)((char*)d_ws + CURA_BYTE_OFF + 134217728);      // 2048*512*32  f16 =  64 MB
    // total ws need ~192.2 MB

    prep_weights<<<(W_TOTAL + 255) / 256, 256, 0, stream>>>(
        sW1, sb1, sW2, sb2, sW3, sb3, jW1, jb1, jW2, jb2, jW3, jb3, wbuf);

    // leaf level: rows = 2048*1024
    mlp_level<true><<<2048, 128, 0, stream>>>(
        leaf_feats, nullptr, curA, nullptr,
        wbuf + OFF_S1, wbuf + OFF_S2, wbuf + OFF_S3,
        2048 * 1024, 0, 0, 0);

    // join levels
    const f16* cin = curA;
    f16* cout = curB;
    int off = 0, lg = 9;
    for (int nlev = 512; nlev >= 1; nlev >>= 1, --lg) {
        int rows   = 2048 * nlev;
        int groups = rows / 16;
        int grid   = groups < 2048 ? groups : 2048;
        mlp_level<false><<<grid, 128, 0, stream>>>(
            internal_feats, cin, cout, (float*)d_out,
            wbuf + OFF_J1, wbuf + OFF_J2, wbuf + OFF_J3,
            rows, lg, off, (nlev == 1) ? 1 : 0);
        off += nlev;
        f16* t = cout; cout = (f16*)cin; cin = t;
    }
}

// Round 2
// 957.480 us; speedup vs baseline: 1.0802x; 1.0802x over previous
//
#include <hip/hip_runtime.h>
#include <hip/hip_bf16.h>

// ---------------------------------------------------------------------------
// PlanStructuredNetwork — round 2.
//   R1: 1034 us, MfmaUtil ~20%, latency-bound (long dependent chain, ~2
//   waves/SIMD). Changes:
//   * bias folded into C-init (f32x4 bias frags) — no augmented K-steps:
//     9 fewer MFMAs/group, no aug-column LDS init, f32 bias precision.
//   * 4-wave blocks, 4-way M-split of L1/L2 (A-regs per wave halved),
//     L3 split by (group, M-half) across the 4 waves.
//   * G=2 independent 16-row groups per iteration: 2 independent MFMA
//     chains, 2x MFMA per barrier.
//   * explicit prefetch of next iteration's global inputs (feats + child
//     cur rows) to hide ~900-cyc cold HBM latency behind compute.
// ws: 114688 B weights + 128 MB curA + 64 MB curB (~192.1 MB).
// ---------------------------------------------------------------------------

typedef _Float16 f16;
typedef _Float16 f16x8 __attribute__((ext_vector_type(8)));
typedef _Float16 f16x4 __attribute__((ext_vector_type(4)));
typedef float    f32x4 __attribute__((ext_vector_type(4)));

#define MFMA16(a, b, c) __builtin_amdgcn_mfma_f32_16x16x32_f16((a), (b), (c), 0, 0, 0)

// ws element offsets (f16) of transposed weights W^T[m][k] (no augmentation)
#define OFF_S1 0       // [128][32]
#define OFF_S2 4096    // [128][128]
#define OFF_S3 20480   // [32][128]
#define OFF_J1 24576   // [128][96]
#define OFF_J2 36864   // [128][128]
#define OFF_J3 53248   // [32][128]
#define W_TOTAL 57344
#define CURA_BYTE_OFF 114688   // = W_TOTAL*2 (448*256, aligned)

__global__ void prep_weights(const float* __restrict__ sW1,
                             const float* __restrict__ sW2,
                             const float* __restrict__ sW3,
                             const float* __restrict__ jW1,
                             const float* __restrict__ jW2,
                             const float* __restrict__ jW3,
                             f16* __restrict__ wbuf)
{
    int idx = blockIdx.x * 256 + threadIdx.x;
    if (idx >= W_TOTAL) return;
    const float* W;
    int off, M, K;
    if (idx < OFF_S2)      { off = OFF_S1; M = 128; K = 32;  W = sW1; }
    else if (idx < OFF_S3) { off = OFF_S2; M = 128; K = 128; W = sW2; }
    else if (idx < OFF_J1) { off = OFF_S3; M = 32;  K = 128; W = sW3; }
    else if (idx < OFF_J2) { off = OFF_J1; M = 128; K = 96;  W = jW1; }
    else if (idx < OFF_J3) { off = OFF_J2; M = 128; K = 128; W = jW2; }
    else                   { off = OFF_J3; M = 32;  K = 128; W = jW3; }
    int r = idx - off;
    int m = r / K;
    int k = r - m * K;
    wbuf[idx] = (f16)W[(size_t)k * M + m];   // W^T[m][k] = W[k][m]
}

// Fused 3-layer MLP level. Block = 256 threads = 4 waves; 32 rows (2 groups
// of 16) per iteration. Wave w owns M-rows [32w,32w+32) of layers 1/2;
// layer 3 (M=32): wave w handles group (w&1), M-half (w>>1).
template <bool LEAF>
__global__ __launch_bounds__(256, 2)
void mlp_level(const float* __restrict__ feats,
               const f16*   __restrict__ cur_in,
               f16*         __restrict__ cur_out,
               float*       __restrict__ out_final,
               const f16*   __restrict__ W1t,
               const f16*   __restrict__ W2t,
               const f16*   __restrict__ W3t,
               const float* __restrict__ b1,
               const float* __restrict__ b2,
               const float* __restrict__ b3,
               int rows, int log2n, int foff, int is_last)
{
    constexpr int K1    = LEAF ? 32 : 96;
    constexpr int NK1   = LEAF ? 1 : 3;   // feats (+ curL + curR) K-steps
    constexpr int PITCH = 136;            // f16/row = 272 B (16B-mult, padded)

    __shared__ __align__(16) f16 h1[32 * PITCH];
    __shared__ __align__(16) f16 h2[32 * PITCH];

    const int tid  = threadIdx.x;
    const int wave = tid >> 6;
    const int lane = tid & 63;
    const int n    = lane & 15;   // node-local index (N dim of MFMA)
    const int q    = lane >> 4;
    const int mrow = 32 * wave;   // L1/L2 M-slice base
    const int l3g  = wave & 1;    // L3: which group
    const int l3h  = wave >> 1;   // L3: which 16-row M-half

    // ---- resident weights (A[m][k]; m = mrow + 16*mt + n, k = 32*ks+8*q+j)
    f16x8 A1[2][NK1], A2[2][4], A3[4];
#pragma unroll
    for (int mt = 0; mt < 2; ++mt)
#pragma unroll
        for (int ks = 0; ks < NK1; ++ks)
            A1[mt][ks] = *(const f16x8*)(W1t + (size_t)(mrow + 16 * mt + n) * K1 + 32 * ks + 8 * q);
#pragma unroll
    for (int mt = 0; mt < 2; ++mt)
#pragma unroll
        for (int ks = 0; ks < 4; ++ks)
            A2[mt][ks] = *(const f16x8*)(W2t + (size_t)(mrow + 16 * mt + n) * 128 + 32 * ks + 8 * q);
#pragma unroll
    for (int ks = 0; ks < 4; ++ks)
        A3[ks] = *(const f16x8*)(W3t + (size_t)(16 * l3h + n) * 128 + 32 * ks + 8 * q);

    // ---- bias fragments: C[mt][reg] row m = mrow + 16*mt + 4*q + reg
    f32x4 bf1[2], bf2[2], bf3;
#pragma unroll
    for (int mt = 0; mt < 2; ++mt) {
        bf1[mt] = *(const f32x4*)(b1 + mrow + 16 * mt + 4 * q);
        bf2[mt] = *(const f32x4*)(b2 + mrow + 16 * mt + 4 * q);
    }
    bf3 = *(const f32x4*)(b3 + 16 * l3h + 4 * q);

    // ---- prefetch state (next iteration's global inputs)
    struct PF {
        f32x4 fa[2], fb[2];   // feats cols 8q..8q+7 per group
        f16x8 cl[2], cr[2];   // join: child rows (unused for leaf)
    };
    auto load_pf = [&](int g0, PF& p) {
#pragma unroll
        for (int g = 0; g < 2; ++g) {
            int gr = g0 + 16 * g + n;
            const float* frow;
            if constexpr (LEAF) {
                frow = feats + (size_t)gr * 32;
            } else {
                int bb = gr >> log2n;
                int ii = gr & ((1 << log2n) - 1);
                frow = feats + ((size_t)bb * 1023 + foff + ii) * 32;
            }
            p.fa[g] = *(const f32x4*)(frow + 8 * q);
            p.fb[g] = *(const f32x4*)(frow + 8 * q + 4);
            if constexpr (!LEAF) {
                p.cl[g] = *(const f16x8*)(cur_in + (size_t)(2 * gr) * 32 + 8 * q);
                p.cr[g] = *(const f16x8*)(cur_in + (size_t)(2 * gr) * 32 + 32 + 8 * q);
            }
        }
    };

    const int stride = gridDim.x * 32;
    int g0 = blockIdx.x * 32;
    PF p;
    if (g0 < rows) load_pf(g0, p);

    for (; g0 < rows; g0 += stride) {
        // issue next iteration's loads first — they drain during compute
        PF pn;
        int gnext = g0 + stride;
        load_pf(gnext < rows ? gnext : g0, pn);

        // ---------------- layer 1 ----------------
        f32x4 C[2][2];
#pragma unroll
        for (int g = 0; g < 2; ++g)
#pragma unroll
            for (int mt = 0; mt < 2; ++mt) C[g][mt] = bf1[mt];

#pragma unroll
        for (int g = 0; g < 2; ++g) {
            f16x8 Bf;
#pragma unroll
            for (int j = 0; j < 4; ++j) {
                Bf[j]     = (f16)p.fa[g][j];
                Bf[4 + j] = (f16)p.fb[g][j];
            }
#pragma unroll
            for (int mt = 0; mt < 2; ++mt) C[g][mt] = MFMA16(A1[mt][0], Bf, C[g][mt]);
            if constexpr (!LEAF) {
#pragma unroll
                for (int mt = 0; mt < 2; ++mt) C[g][mt] = MFMA16(A1[mt][1], p.cl[g], C[g][mt]);
#pragma unroll
                for (int mt = 0; mt < 2; ++mt) C[g][mt] = MFMA16(A1[mt][2], p.cr[g], C[g][mt]);
            }
        }
        // relu + pack -> h1[16g+n][mrow + 16mt + 4q + reg]
#pragma unroll
        for (int g = 0; g < 2; ++g)
#pragma unroll
            for (int mt = 0; mt < 2; ++mt) {
                f16x4 pk;
                pk[0] = (f16)fmaxf(C[g][mt][0], 0.0f);
                pk[1] = (f16)fmaxf(C[g][mt][1], 0.0f);
                pk[2] = (f16)fmaxf(C[g][mt][2], 0.0f);
                pk[3] = (f16)fmaxf(C[g][mt][3], 0.0f);
                *(f16x4*)(h1 + (16 * g + n) * PITCH + mrow + 16 * mt + 4 * q) = pk;
            }
        __syncthreads();

        // ---------------- layer 2 ----------------
#pragma unroll
        for (int g = 0; g < 2; ++g)
#pragma unroll
            for (int mt = 0; mt < 2; ++mt) C[g][mt] = bf2[mt];
#pragma unroll
        for (int ks = 0; ks < 4; ++ks)
#pragma unroll
            for (int g = 0; g < 2; ++g) {
                f16x8 Bf = *(const f16x8*)(h1 + (16 * g + n) * PITCH + 32 * ks + 8 * q);
#pragma unroll
                for (int mt = 0; mt < 2; ++mt) C[g][mt] = MFMA16(A2[mt][ks], Bf, C[g][mt]);
            }
#pragma unroll
        for (int g = 0; g < 2; ++g)
#pragma unroll
            for (int mt = 0; mt < 2; ++mt) {
                f16x4 pk;
                pk[0] = (f16)fmaxf(C[g][mt][0], 0.0f);
                pk[1] = (f16)fmaxf(C[g][mt][1], 0.0f);
                pk[2] = (f16)fmaxf(C[g][mt][2], 0.0f);
                pk[3] = (f16)fmaxf(C[g][mt][3], 0.0f);
                *(f16x4*)(h2 + (16 * g + n) * PITCH + mrow + 16 * mt + 4 * q) = pk;
            }
        __syncthreads();

        // ---------------- layer 3 (wave -> group l3g, M-half l3h) --------
        f32x4 C3 = bf3;
#pragma unroll
        for (int ks = 0; ks < 4; ++ks) {
            f16x8 Bf = *(const f16x8*)(h2 + (16 * l3g + n) * PITCH + 32 * ks + 8 * q);
            C3 = MFMA16(A3[ks], Bf, C3);
        }

        if (is_last) {
            // out[b] = cur[:,0,0]: o=0 -> l3h==0, q==0, reg 0
            if (l3h == 0 && q == 0) out_final[g0 + 16 * l3g + n] = C3[0];
        } else {
            f16x4 pk;
            pk[0] = (f16)C3[0]; pk[1] = (f16)C3[1]; pk[2] = (f16)C3[2]; pk[3] = (f16)C3[3];
            *(f16x4*)(cur_out + (size_t)(g0 + 16 * l3g + n) * 32 + 16 * l3h + 4 * q) = pk;
        }
        // next-iter h1 writes are fenced by this iter's barriers (see R1 note)

        p = pn;
    }
}

extern "C" void kernel_launch(void* const* d_in, const int* in_sizes, int n_in,
                              void* d_out, int out_size, void* d_ws, size_t ws_size,
                              hipStream_t stream)
{
    const float* leaf_feats     = (const float*)d_in[0];
    const float* internal_feats = (const float*)d_in[1];
    const float* sW1 = (const float*)d_in[2];  const float* sb1 = (const float*)d_in[3];
    const float* sW2 = (const float*)d_in[4];  const float* sb2 = (const float*)d_in[5];
    const float* sW3 = (const float*)d_in[6];  const float* sb3 = (const float*)d_in[7];
    const float* jW1 = (const float*)d_in[8];  const float* jb1 = (const float*)d_in[9];
    const float* jW2 = (const float*)d_in[10]; const float* jb2 = (const float*)d_in[11];
    const float* jW3 = (const float*)d_in[12]; const float* jb3 = (const float*)d_in[13];

    f16* wbuf = (f16*)d_ws;
    f16* curA = (f16*)((char*)d_ws + CURA_BYTE_OFF);                 // 128 MB
    f16* curB = (f16*)((char*)d_ws + CURA_BYTE_OFF + 134217728);     // 64 MB

    prep_weights<<<(W_TOTAL + 255) / 256, 256, 0, stream>>>(
        sW1, sW2, sW3, jW1, jW2, jW3, wbuf);

    // leaf level: 2048*1024 rows, 65536 iterations of 32 rows
    mlp_level<true><<<2048, 256, 0, stream>>>(
        leaf_feats, nullptr, curA, nullptr,
        wbuf + OFF_S1, wbuf + OFF_S2, wbuf + OFF_S3,
        sb1, sb2, sb3,
        2048 * 1024, 0, 0, 0);

    // join levels
    const f16* cin = curA;
    f16* cout = curB;
    int off = 0, lg = 9;
    for (int nlev = 512; nlev >= 1; nlev >>= 1, --lg) {
        int rows  = 2048 * nlev;
        int iters = rows / 32;
        int grid  = iters < 2048 ? iters : 2048;
        mlp_level<false><<<grid, 256, 0, stream>>>(
            internal_feats, cin, cout, (float*)d_out,
            wbuf + OFF_J1, wbuf + OFF_J2, wbuf + OFF_J3,
            jb1, jb2, jb3,
            rows, lg, off, (nlev == 1) ? 1 : 0);
        off += nlev;
        f16* t = cout; cout = (f16*)cin; cin = t;
    }
}